// Round 2
// baseline (494.067 us; speedup 1.0000x reference)
//
#include <hip/hip_runtime.h>
#include <hip/hip_bf16.h>

typedef __attribute__((ext_vector_type(8))) short short8;
typedef __attribute__((ext_vector_type(4))) float f32x4;

#define EPS 1e-5f

__device__ __forceinline__ unsigned short f2bf(float f) {
    union { float f; unsigned u; } v; v.f = f;
    unsigned u = v.u;
    u += 0x7FFFu + ((u >> 16) & 1u);   // RNE
    return (unsigned short)(u >> 16);
}
__device__ __forceinline__ float bflo(unsigned u) {
    union { unsigned u; float f; } v; v.u = u << 16; return v.f;
}
__device__ __forceinline__ float bfhi(unsigned u) {
    union { unsigned u; float f; } v; v.u = u & 0xffff0000u; return v.f;
}

// load 8 consecutive f32, convert to a bf16x8 MFMA fragment
__device__ __forceinline__ short8 load_frag_f32(const float* __restrict__ p) {
    f32x4 a = *(const f32x4*)p;
    f32x4 b = *(const f32x4*)(p + 4);
    short8 r;
    r[0] = (short)f2bf(a[0]); r[1] = (short)f2bf(a[1]);
    r[2] = (short)f2bf(a[2]); r[3] = (short)f2bf(a[3]);
    r[4] = (short)f2bf(b[0]); r[5] = (short)f2bf(b[1]);
    r[6] = (short)f2bf(b[2]); r[7] = (short)f2bf(b[3]);
    return r;
}

// ---------------- K0: one-time weight conversion f32 -> bf16 ----------------
__global__ __launch_bounds__(256) void k_prep(
        const float* __restrict__ ipw, const float* __restrict__ ow,
        const float* __restrict__ w1, const float* __restrict__ w2,
        ushort* __restrict__ wqb, ushort* __restrict__ wob,
        ushort* __restrict__ w1b, ushort* __restrict__ w2b) {
    int i = blockIdx.x * 256 + threadIdx.x;      // grid covers 65536
    if (i < 49152) wqb[i] = f2bf(ipw[i]);
    if (i < 16384) wob[i] = f2bf(ow[i]);
    w1b[i] = f2bf(w1[i]);
    w2b[i] = f2bf(w2[i]);
}

// ---------------- K1: qkv = x @ in_proj_w^T + b  (bf16 out) ----------------
__global__ __launch_bounds__(256) void k_qkv(
        const float* __restrict__ x, const ushort* __restrict__ w,
        const float* __restrict__ bias, ushort* __restrict__ qkv, int N) {
    const int wave = threadIdx.x >> 6, lane = threadIdx.x & 63;
    const int l16 = lane & 15, l4 = lane >> 4;
    const int base = blockIdx.x * 64;

    short8 af[4][4];
    #pragma unroll
    for (int mt = 0; mt < 4; ++mt) {
        int row = base + mt*16 + l16;
        int rc = row < N ? row : N - 1;
        const float* p = x + (size_t)rc*128 + l4*8;
        #pragma unroll
        for (int kb = 0; kb < 4; ++kb) af[mt][kb] = load_frag_f32(p + kb*32);
    }
    #pragma unroll
    for (int i = 0; i < 6; ++i) {
        int col = (wave*6 + i)*16 + l16;
        const ushort* pw = w + (size_t)col*128 + l4*8;
        short8 bf[4];
        #pragma unroll
        for (int kb = 0; kb < 4; ++kb) bf[kb] = *(const short8*)(pw + kb*32);
        float bv = bias[col];
        #pragma unroll
        for (int mt = 0; mt < 4; ++mt) {
            f32x4 acc = {0.f, 0.f, 0.f, 0.f};
            #pragma unroll
            for (int kb = 0; kb < 4; ++kb)
                acc = __builtin_amdgcn_mfma_f32_16x16x32_bf16(af[mt][kb], bf[kb], acc, 0, 0, 0);
            #pragma unroll
            for (int r = 0; r < 4; ++r) {
                int row = base + mt*16 + l4*4 + r;
                if (row < N) qkv[(size_t)row*384 + col] = f2bf(acc[r] + bv);
            }
        }
    }
}

// ---------------- K2: sampled attention; ctx written into dead Q region ----
// one wave per node; lane = (k = lane&15, head-pair hp = lane>>4 -> heads hp, hp+4)
__global__ __launch_bounds__(256) void k_attn(
        ushort* __restrict__ qkv, const int* __restrict__ samp, int N) {
    const int wave = threadIdx.x >> 6, lane = threadIdx.x & 63;
    const int n = blockIdx.x * 4 + wave;
    if (n >= N) return;
    const int k  = lane & 15;
    const int hp = lane >> 4;
    const int h0 = hp, h1 = hp + 4;

    const int idx = samp[(size_t)n*16 + k];
    const ushort* qrow = qkv + (size_t)n*384;
    const ushort* krow = qkv + (size_t)idx*384 + 128;
    const ushort* vrow = qkv + (size_t)idx*384 + 256;

    float s0 = 0.f, s1 = 0.f;
    {
        const uint4* qa = (const uint4*)(qrow + h0*16);
        const uint4* ka = (const uint4*)(krow + h0*16);
        const uint4* qb = (const uint4*)(qrow + h1*16);
        const uint4* kb = (const uint4*)(krow + h1*16);
        #pragma unroll
        for (int i = 0; i < 2; ++i) {
            uint4 ua = qa[i], va = ka[i], ub = qb[i], vb = kb[i];
            s0 += bflo(ua.x)*bflo(va.x) + bfhi(ua.x)*bfhi(va.x)
                + bflo(ua.y)*bflo(va.y) + bfhi(ua.y)*bfhi(va.y)
                + bflo(ua.z)*bflo(va.z) + bfhi(ua.z)*bfhi(va.z)
                + bflo(ua.w)*bflo(va.w) + bfhi(ua.w)*bfhi(va.w);
            s1 += bflo(ub.x)*bflo(vb.x) + bfhi(ub.x)*bfhi(vb.x)
                + bflo(ub.y)*bflo(vb.y) + bfhi(ub.y)*bfhi(vb.y)
                + bflo(ub.z)*bflo(vb.z) + bfhi(ub.z)*bfhi(vb.z)
                + bflo(ub.w)*bflo(vb.w) + bfhi(ub.w)*bfhi(vb.w);
        }
    }
    s0 *= 0.25f; s1 *= 0.25f;     // 1/sqrt(16)
    float m0 = s0, m1 = s1;
    #pragma unroll
    for (int off = 1; off < 16; off <<= 1) {
        m0 = fmaxf(m0, __shfl_xor(m0, off));
        m1 = fmaxf(m1, __shfl_xor(m1, off));
    }
    float e0 = __expf(s0 - m0), e1 = __expf(s1 - m1);
    float d0 = e0, d1 = e1;
    #pragma unroll
    for (int off = 1; off < 16; off <<= 1) {
        d0 += __shfl_xor(d0, off);
        d1 += __shfl_xor(d1, off);
    }
    float a0 = e0 / d0, a1 = e1 / d1;

    float v0[16], v1[16];
    {
        const uint4* p0 = (const uint4*)(vrow + h0*16);
        const uint4* p1 = (const uint4*)(vrow + h1*16);
        #pragma unroll
        for (int i = 0; i < 2; ++i) {
            uint4 ua = p0[i], ub = p1[i];
            v0[8*i+0] = a0*bflo(ua.x); v0[8*i+1] = a0*bfhi(ua.x);
            v0[8*i+2] = a0*bflo(ua.y); v0[8*i+3] = a0*bfhi(ua.y);
            v0[8*i+4] = a0*bflo(ua.z); v0[8*i+5] = a0*bfhi(ua.z);
            v0[8*i+6] = a0*bflo(ua.w); v0[8*i+7] = a0*bfhi(ua.w);
            v1[8*i+0] = a1*bflo(ub.x); v1[8*i+1] = a1*bfhi(ub.x);
            v1[8*i+2] = a1*bflo(ub.y); v1[8*i+3] = a1*bfhi(ub.y);
            v1[8*i+4] = a1*bflo(ub.z); v1[8*i+5] = a1*bfhi(ub.z);
            v1[8*i+6] = a1*bflo(ub.w); v1[8*i+7] = a1*bfhi(ub.w);
        }
    }
    // recursive-halving reduce over the 16 k-lanes: 15 shuffles/head instead of 64
    #pragma unroll
    for (int bit = 0; bit < 4; ++bit) {
        const int m = 1 << bit;
        const int half = 8 >> bit;          // 8,4,2,1
        const bool up = (k >> bit) & 1;
        #pragma unroll
        for (int i = 0; i < half; ++i) {
            float s0v = up ? v0[i] : v0[i + half];
            float s1v = up ? v1[i] : v1[i + half];
            float r0 = __shfl_xor(s0v, m);
            float r1 = __shfl_xor(s1v, m);
            v0[i] = (up ? v0[i + half] : v0[i]) + r0;
            v1[i] = (up ? v1[i + half] : v1[i]) + r1;
        }
    }
    // lane k now owns dim d = bit-reverse4(k), fully summed
    const int d = ((k & 1) << 3) | ((k & 2) << 1) | ((k & 4) >> 1) | ((k & 8) >> 3);
    // write ctx into the dead Q region of this node's qkv row
    qkv[(size_t)n*384 + h0*16 + d] = f2bf(v0[0]);
    qkv[(size_t)n*384 + h1*16 + d] = f2bf(v1[0]);
}

// ---------------- K3: y = LN1(x + ctx @ out_w^T + out_b) ----------------
__global__ __launch_bounds__(256) void k_oproj(
        const ushort* __restrict__ ctx, const ushort* __restrict__ ow,
        const float* __restrict__ ob, const float* __restrict__ x,
        const float* __restrict__ g1, const float* __restrict__ be1,
        float* __restrict__ y, int N) {
    const int wave = threadIdx.x >> 6, lane = threadIdx.x & 63;
    const int l16 = lane & 15, l4 = lane >> 4;
    const int mbase = blockIdx.x * 64 + wave * 16;

    short8 af[4];
    {
        int row = mbase + l16;
        int rc = row < N ? row : N - 1;
        const ushort* p = ctx + (size_t)rc*384 + l4*8;   // ctx lives at qkv row offset 0
        #pragma unroll
        for (int kb = 0; kb < 4; ++kb) af[kb] = *(const short8*)(p + kb*32);
    }
    f32x4 acc[8];
    #pragma unroll
    for (int nt = 0; nt < 8; ++nt) {
        int col = nt*16 + l16;
        const ushort* pw = ow + (size_t)col*128 + l4*8;
        f32x4 a = {0.f, 0.f, 0.f, 0.f};
        #pragma unroll
        for (int kb = 0; kb < 4; ++kb) {
            short8 bf = *(const short8*)(pw + kb*32);
            a = __builtin_amdgcn_mfma_f32_16x16x32_bf16(af[kb], bf, a, 0, 0, 0);
        }
        acc[nt] = a;
    }
    #pragma unroll
    for (int r = 0; r < 4; ++r) {
        int row = mbase + l4*4 + r;
        bool ok = row < N;
        int rc = ok ? row : N - 1;
        float s[8];
        float sum = 0.f, sq = 0.f;
        #pragma unroll
        for (int nt = 0; nt < 8; ++nt) {
            int col = nt*16 + l16;
            float v = acc[nt][r] + ob[col] + x[(size_t)rc*128 + col];
            s[nt] = v; sum += v; sq += v*v;
        }
        #pragma unroll
        for (int off = 1; off < 16; off <<= 1) {
            sum += __shfl_xor(sum, off);
            sq  += __shfl_xor(sq, off);
        }
        float mean = sum * (1.f/128.f);
        float rstd = rsqrtf(sq*(1.f/128.f) - mean*mean + EPS);
        if (ok) {
            #pragma unroll
            for (int nt = 0; nt < 8; ++nt) {
                int col = nt*16 + l16;
                y[(size_t)row*128 + col] = (s[nt]-mean)*rstd*g1[col] + be1[col];
            }
        }
    }
}

// ---------------- K4: out = LN2(y + relu(y@w1^T+b1)@w2^T + b2) ----------------
__global__ __launch_bounds__(256) void k_ffn(
        const float* yin, const ushort* __restrict__ w1, const float* __restrict__ b1,
        const ushort* __restrict__ w2, const float* __restrict__ b2,
        const float* __restrict__ g2, const float* __restrict__ be2,
        float* out, int N) {
    __shared__ __align__(16) char smem[65536];
    float* sbuf = (float*)smem;                 // [64][132] f32 after stage2
    const int wave = threadIdx.x >> 6, lane = threadIdx.x & 63;
    const int l16 = lane & 15, l4 = lane >> 4;
    const int base = blockIdx.x * 64;

    // ---- stage 1 ----
    short8 af[4][4];
    #pragma unroll
    for (int mt = 0; mt < 4; ++mt) {
        int row = base + mt*16 + l16;
        int rc = row < N ? row : N - 1;
        const float* p = yin + (size_t)rc*128 + l4*8;
        #pragma unroll
        for (int kb = 0; kb < 4; ++kb) af[mt][kb] = load_frag_f32(p + kb*32);
    }
    #pragma unroll
    for (int i = 0; i < 8; ++i) {
        int col = (wave*8 + i)*16 + l16;
        const ushort* pw = w1 + (size_t)col*128 + l4*8;
        short8 bf[4];
        #pragma unroll
        for (int kb = 0; kb < 4; ++kb) bf[kb] = *(const short8*)(pw + kb*32);
        float bv = b1[col];
        #pragma unroll
        for (int mt = 0; mt < 4; ++mt) {
            f32x4 acc = {0.f, 0.f, 0.f, 0.f};
            #pragma unroll
            for (int kb = 0; kb < 4; ++kb)
                acc = __builtin_amdgcn_mfma_f32_16x16x32_bf16(af[mt][kb], bf[kb], acc, 0, 0, 0);
            #pragma unroll
            for (int r = 0; r < 4; ++r) {
                int row = mt*16 + l4*4 + r;        // row within tile
                float v = acc[r] + bv;
                v = v > 0.f ? v : 0.f;
                int byteoff = row*1024 + ((col*2) ^ ((row & 7) << 4));
                *(ushort*)(smem + byteoff) = f2bf(v);
            }
        }
    }
    __syncthreads();

    // ---- stage 2: wave handles n-tiles {2w, 2w+1} x 4 m-tiles, K=512 ----
    f32x4 acc2[4][2];
    #pragma unroll
    for (int mt = 0; mt < 4; ++mt)
        #pragma unroll
        for (int ntl = 0; ntl < 2; ++ntl) acc2[mt][ntl] = (f32x4){0.f,0.f,0.f,0.f};
    #pragma unroll 4
    for (int kb = 0; kb < 16; ++kb) {
        short8 a2[4];
        #pragma unroll
        for (int mt = 0; mt < 4; ++mt) {
            int row = mt*16 + l16;
            int kbyte = kb*64 + l4*16;
            a2[mt] = *(const short8*)(smem + row*1024 + (kbyte ^ ((row & 7) << 4)));
        }
        #pragma unroll
        for (int ntl = 0; ntl < 2; ++ntl) {
            int col = (wave*2 + ntl)*16 + l16;
            short8 bfr = *(const short8*)(w2 + (size_t)col*512 + kb*32 + l4*8);
            #pragma unroll
            for (int mt = 0; mt < 4; ++mt)
                acc2[mt][ntl] = __builtin_amdgcn_mfma_f32_16x16x32_bf16(a2[mt], bfr, acc2[mt][ntl], 0, 0, 0);
        }
    }
    __syncthreads();
    // ---- s = y + ff -> sbuf ----
    #pragma unroll
    for (int mt = 0; mt < 4; ++mt) {
        #pragma unroll
        for (int ntl = 0; ntl < 2; ++ntl) {
            int col = (wave*2 + ntl)*16 + l16;
            float bv = b2[col];
            #pragma unroll
            for (int r = 0; r < 4; ++r) {
                int row = mt*16 + l4*4 + r;
                int grow = base + row;
                int rc = grow < N ? grow : N - 1;
                sbuf[row*132 + col] = yin[(size_t)rc*128 + col] + acc2[mt][ntl][r] + bv;
            }
        }
    }
    __syncthreads();
    // ---- LN2: 4 threads per row ----
    {
        int row = threadIdx.x >> 2;     // 0..63
        int sub = threadIdx.x & 3;
        const float* sp = sbuf + row*132 + sub*32;
        float vals[32];
        float sum = 0.f, sq = 0.f;
        #pragma unroll
        for (int i = 0; i < 32; ++i) { float v = sp[i]; vals[i] = v; sum += v; sq += v*v; }
        sum += __shfl_xor(sum, 1); sq += __shfl_xor(sq, 1);
        sum += __shfl_xor(sum, 2); sq += __shfl_xor(sq, 2);
        float mean = sum * (1.f/128.f);
        float rstd = rsqrtf(sq*(1.f/128.f) - mean*mean + EPS);
        int grow = base + row;
        if (grow < N) {
            float* po = out + (size_t)grow*128 + sub*32;
            const float* pg = g2 + sub*32;
            const float* pb = be2 + sub*32;
            #pragma unroll
            for (int i = 0; i < 32; ++i)
                po[i] = (vals[i]-mean)*rstd*pg[i] + pb[i];
        }
    }
}

extern "C" void kernel_launch(void* const* d_in, const int* in_sizes, int n_in,
                              void* d_out, int out_size, void* d_ws, size_t ws_size,
                              hipStream_t stream) {
    (void)n_in; (void)out_size; (void)ws_size;
    const float* x   = (const float*)d_in[0];
    const int*   smp = (const int*)  d_in[1];
    const float* ipw = (const float*)d_in[2];
    const float* ipb = (const float*)d_in[3];
    const float* ow  = (const float*)d_in[4];
    const float* ob  = (const float*)d_in[5];
    const float* w1  = (const float*)d_in[6];
    const float* b1  = (const float*)d_in[7];
    const float* w2  = (const float*)d_in[8];
    const float* b2  = (const float*)d_in[9];
    const float* g1  = (const float*)d_in[10];
    const float* be1 = (const float*)d_in[11];
    const float* g2  = (const float*)d_in[12];
    const float* be2 = (const float*)d_in[13];
    const int N = in_sizes[0] / 128;

    ushort* qkv  = (ushort*)d_ws;                   // [N][384] bf16; Q region reused as ctx
    ushort* wqb  = qkv + (size_t)N * 384;           // 384*128
    ushort* wob  = wqb + 384*128;                   // 128*128
    ushort* w1b  = wob + 128*128;                   // 512*128
    ushort* w2b  = w1b + 512*128;                   // 128*512
    float*  y    = (float*)d_out;                   // staged y, then final out

    const int nb = (N + 63) / 64;
    k_prep <<<256,       256, 0, stream>>>(ipw, ow, w1, w2, wqb, wob, w1b, w2b);
    k_qkv  <<<nb,        256, 0, stream>>>(x, wqb, ipb, qkv, N);
    k_attn <<<(N+3)/4,   256, 0, stream>>>(qkv, smp, N);
    k_oproj<<<nb,        256, 0, stream>>>(qkv, wob, ob, x, g1, be1, y, N);
    k_ffn  <<<nb,        256, 0, stream>>>(y, w1b, b1, w2b, b2, g2, be2, y, N);
}

// Round 3
// 314.123 us; speedup vs baseline: 1.5728x; 1.5728x over previous
//
#include <hip/hip_runtime.h>
#include <hip/hip_bf16.h>

typedef __attribute__((ext_vector_type(8))) short short8;
typedef __attribute__((ext_vector_type(4))) float f32x4;

#define EPS 1e-5f

__device__ __forceinline__ unsigned short f2bf(float f) {
    union { float f; unsigned u; } v; v.f = f;
    unsigned u = v.u;
    u += 0x7FFFu + ((u >> 16) & 1u);   // RNE
    return (unsigned short)(u >> 16);
}
__device__ __forceinline__ float bflo(unsigned u) {
    union { unsigned u; float f; } v; v.u = u << 16; return v.f;
}
__device__ __forceinline__ float bfhi(unsigned u) {
    union { unsigned u; float f; } v; v.u = u & 0xffff0000u; return v.f;
}
__device__ __forceinline__ float bf2f(ushort u) {
    union { unsigned u; float f; } v; v.u = ((unsigned)u) << 16; return v.f;
}

// load 8 consecutive f32, convert to a bf16x8 MFMA fragment
__device__ __forceinline__ short8 load_frag_f32(const float* __restrict__ p) {
    f32x4 a = *(const f32x4*)p;
    f32x4 b = *(const f32x4*)(p + 4);
    short8 r;
    r[0] = (short)f2bf(a[0]); r[1] = (short)f2bf(a[1]);
    r[2] = (short)f2bf(a[2]); r[3] = (short)f2bf(a[3]);
    r[4] = (short)f2bf(b[0]); r[5] = (short)f2bf(b[1]);
    r[6] = (short)f2bf(b[2]); r[7] = (short)f2bf(b[3]);
    return r;
}

// ---------------- K0: one-time weight conversion f32 -> bf16 ----------------
__global__ __launch_bounds__(256) void k_prep(
        const float* __restrict__ ipw, const float* __restrict__ ow,
        const float* __restrict__ w1, const float* __restrict__ w2,
        ushort* __restrict__ wqb, ushort* __restrict__ wob,
        ushort* __restrict__ w1b, ushort* __restrict__ w2b) {
    int i = blockIdx.x * 256 + threadIdx.x;      // grid covers 65536
    if (i < 49152) wqb[i] = f2bf(ipw[i]);
    if (i < 16384) wob[i] = f2bf(ow[i]);
    w1b[i] = f2bf(w1[i]);
    w2b[i] = f2bf(w2[i]);
}

// ---------------- K1: qkv = x @ in_proj_w^T + b  (bf16 out) ----------------
__global__ __launch_bounds__(256) void k_qkv(
        const float* __restrict__ x, const ushort* __restrict__ w,
        const float* __restrict__ bias, ushort* __restrict__ qkv, int N) {
    const int wave = threadIdx.x >> 6, lane = threadIdx.x & 63;
    const int l16 = lane & 15, l4 = lane >> 4;
    const int base = blockIdx.x * 64;

    short8 af[4][4];
    #pragma unroll
    for (int mt = 0; mt < 4; ++mt) {
        int row = base + mt*16 + l16;
        int rc = row < N ? row : N - 1;
        const float* p = x + (size_t)rc*128 + l4*8;
        #pragma unroll
        for (int kb = 0; kb < 4; ++kb) af[mt][kb] = load_frag_f32(p + kb*32);
    }
    #pragma unroll
    for (int i = 0; i < 6; ++i) {
        int col = (wave*6 + i)*16 + l16;
        const ushort* pw = w + (size_t)col*128 + l4*8;
        short8 bf[4];
        #pragma unroll
        for (int kb = 0; kb < 4; ++kb) bf[kb] = *(const short8*)(pw + kb*32);
        float bv = bias[col];
        #pragma unroll
        for (int mt = 0; mt < 4; ++mt) {
            f32x4 acc = {0.f, 0.f, 0.f, 0.f};
            #pragma unroll
            for (int kb = 0; kb < 4; ++kb)
                acc = __builtin_amdgcn_mfma_f32_16x16x32_bf16(af[mt][kb], bf[kb], acc, 0, 0, 0);
            #pragma unroll
            for (int r = 0; r < 4; ++r) {
                int row = base + mt*16 + l4*4 + r;
                if (row < N) qkv[(size_t)row*384 + col] = f2bf(acc[r] + bv);
            }
        }
    }
}

// ---------------- K2: sampled attention; ctx written into dead Q region ----
// Phase 1: lane=(k=lane&15, hp=lane>>4) computes softmax weights for heads hp, hp+4.
// Weights go to wave-local LDS (no barrier needed). Phase 2: lane=(h=lane>>3,
// dp=lane&7); per k the V-row load is one fully-coalesced 256B wave transaction
// (SGPR-uniform base via readlane), weight is an LDS broadcast.
__global__ __launch_bounds__(256) void k_attn(
        ushort* __restrict__ qkv, const int* __restrict__ samp, int N) {
    __shared__ float aw[4][8][17];              // [wave][head][k], padded
    const int wave = threadIdx.x >> 6, lane = threadIdx.x & 63;
    const int n = blockIdx.x * 4 + wave;
    if (n >= N) return;
    const int k  = lane & 15;
    const int hp = lane >> 4;
    const int h0 = hp, h1 = hp + 4;

    const int idx = samp[(size_t)n*16 + k];
    const ushort* qrow = qkv + (size_t)n*384;
    const ushort* krow = qkv + (size_t)idx*384 + 128;

    float s0 = 0.f, s1 = 0.f;
    {
        const uint4* qa = (const uint4*)(qrow + h0*16);
        const uint4* ka = (const uint4*)(krow + h0*16);
        const uint4* qb = (const uint4*)(qrow + h1*16);
        const uint4* kb = (const uint4*)(krow + h1*16);
        #pragma unroll
        for (int i = 0; i < 2; ++i) {
            uint4 ua = qa[i], va = ka[i], ub = qb[i], vb = kb[i];
            s0 += bflo(ua.x)*bflo(va.x) + bfhi(ua.x)*bfhi(va.x)
                + bflo(ua.y)*bflo(va.y) + bfhi(ua.y)*bfhi(va.y)
                + bflo(ua.z)*bflo(va.z) + bfhi(ua.z)*bfhi(va.z)
                + bflo(ua.w)*bflo(va.w) + bfhi(ua.w)*bfhi(va.w);
            s1 += bflo(ub.x)*bflo(vb.x) + bfhi(ub.x)*bfhi(vb.x)
                + bflo(ub.y)*bflo(vb.y) + bfhi(ub.y)*bfhi(vb.y)
                + bflo(ub.z)*bflo(vb.z) + bfhi(ub.z)*bfhi(vb.z)
                + bflo(ub.w)*bflo(vb.w) + bfhi(ub.w)*bfhi(vb.w);
        }
    }
    s0 *= 0.25f; s1 *= 0.25f;     // 1/sqrt(16)
    float m0 = s0, m1 = s1;
    #pragma unroll
    for (int off = 1; off < 16; off <<= 1) {
        m0 = fmaxf(m0, __shfl_xor(m0, off));
        m1 = fmaxf(m1, __shfl_xor(m1, off));
    }
    float e0 = __expf(s0 - m0), e1 = __expf(s1 - m1);
    float d0 = e0, d1 = e1;
    #pragma unroll
    for (int off = 1; off < 16; off <<= 1) {
        d0 += __shfl_xor(d0, off);
        d1 += __shfl_xor(d1, off);
    }
    aw[wave][h0][k] = e0 / d0;
    aw[wave][h1][k] = e1 / d1;

    // ---- phase 2: lane = (h, dp); dims d = 2*dp, 2*dp+1 of head h ----
    const int h  = lane >> 3;
    const int dp = lane & 7;
    const float* awl = &aw[wave][0][0];
    const ushort* vtab = qkv + 256;             // V region base
    const int eoff = (h << 4) + (dp << 1);      // element offset within row

    unsigned uv[16];
    #pragma unroll
    for (int kk = 0; kk < 16; ++kk) {
        int rowk = __builtin_amdgcn_readlane(idx, kk);
        uv[kk] = *(const unsigned*)(vtab + (size_t)(unsigned)rowk*384 + eoff);
    }
    float c0a = 0.f, c1a = 0.f, c0b = 0.f, c1b = 0.f;
    #pragma unroll
    for (int kk = 0; kk < 16; kk += 2) {
        float wa = awl[h*17 + kk];
        float wb = awl[h*17 + kk + 1];
        c0a = fmaf(wa, bflo(uv[kk]),   c0a);
        c1a = fmaf(wa, bfhi(uv[kk]),   c1a);
        c0b = fmaf(wb, bflo(uv[kk+1]), c0b);
        c1b = fmaf(wb, bfhi(uv[kk+1]), c1b);
    }
    float c0 = c0a + c0b, c1 = c1a + c1b;
    unsigned pack = (unsigned)f2bf(c0) | ((unsigned)f2bf(c1) << 16);
    *(unsigned*)(qkv + (size_t)n*384 + eoff) = pack;   // ctx into dead Q region
}

// ---------------- K3: y = LN1(x + ctx @ out_w^T + out_b) -> bf16 ----------------
__global__ __launch_bounds__(256) void k_oproj(
        const ushort* __restrict__ ctx, const ushort* __restrict__ ow,
        const float* __restrict__ ob, const float* __restrict__ x,
        const float* __restrict__ g1, const float* __restrict__ be1,
        ushort* __restrict__ y, int N) {
    const int wave = threadIdx.x >> 6, lane = threadIdx.x & 63;
    const int l16 = lane & 15, l4 = lane >> 4;
    const int mbase = blockIdx.x * 64 + wave * 16;

    short8 af[4];
    {
        int row = mbase + l16;
        int rc = row < N ? row : N - 1;
        const ushort* p = ctx + (size_t)rc*384 + l4*8;   // ctx lives at qkv row offset 0
        #pragma unroll
        for (int kb = 0; kb < 4; ++kb) af[kb] = *(const short8*)(p + kb*32);
    }
    f32x4 acc[8];
    #pragma unroll
    for (int nt = 0; nt < 8; ++nt) {
        int col = nt*16 + l16;
        const ushort* pw = ow + (size_t)col*128 + l4*8;
        f32x4 a = {0.f, 0.f, 0.f, 0.f};
        #pragma unroll
        for (int kb = 0; kb < 4; ++kb) {
            short8 bf = *(const short8*)(pw + kb*32);
            a = __builtin_amdgcn_mfma_f32_16x16x32_bf16(af[kb], bf, a, 0, 0, 0);
        }
        acc[nt] = a;
    }
    #pragma unroll
    for (int r = 0; r < 4; ++r) {
        int row = mbase + l4*4 + r;
        bool ok = row < N;
        int rc = ok ? row : N - 1;
        float s[8];
        float sum = 0.f, sq = 0.f;
        #pragma unroll
        for (int nt = 0; nt < 8; ++nt) {
            int col = nt*16 + l16;
            float v = acc[nt][r] + ob[col] + x[(size_t)rc*128 + col];
            s[nt] = v; sum += v; sq += v*v;
        }
        #pragma unroll
        for (int off = 1; off < 16; off <<= 1) {
            sum += __shfl_xor(sum, off);
            sq  += __shfl_xor(sq, off);
        }
        float mean = sum * (1.f/128.f);
        float rstd = rsqrtf(sq*(1.f/128.f) - mean*mean + EPS);
        if (ok) {
            #pragma unroll
            for (int nt = 0; nt < 8; ++nt) {
                int col = nt*16 + l16;
                y[(size_t)row*128 + col] = f2bf((s[nt]-mean)*rstd*g1[col] + be1[col]);
            }
        }
    }
}

// ---------------- K4: out = LN2(y + relu(y@w1^T+b1)@w2^T + b2) ----------------
__global__ __launch_bounds__(256) void k_ffn(
        const ushort* __restrict__ yin, const ushort* __restrict__ w1,
        const float* __restrict__ b1,
        const ushort* __restrict__ w2, const float* __restrict__ b2,
        const float* __restrict__ g2, const float* __restrict__ be2,
        float* __restrict__ out, int N) {
    __shared__ __align__(16) char smem[65536];
    float* sbuf = (float*)smem;                 // [64][132] f32 after stage2
    const int wave = threadIdx.x >> 6, lane = threadIdx.x & 63;
    const int l16 = lane & 15, l4 = lane >> 4;
    const int base = blockIdx.x * 64;

    // ---- stage 1 ----
    short8 af[4][4];
    #pragma unroll
    for (int mt = 0; mt < 4; ++mt) {
        int row = base + mt*16 + l16;
        int rc = row < N ? row : N - 1;
        const ushort* p = yin + (size_t)rc*128 + l4*8;
        #pragma unroll
        for (int kb = 0; kb < 4; ++kb) af[mt][kb] = *(const short8*)(p + kb*32);
    }
    #pragma unroll
    for (int i = 0; i < 8; ++i) {
        int col = (wave*8 + i)*16 + l16;
        const ushort* pw = w1 + (size_t)col*128 + l4*8;
        short8 bf[4];
        #pragma unroll
        for (int kb = 0; kb < 4; ++kb) bf[kb] = *(const short8*)(pw + kb*32);
        float bv = b1[col];
        #pragma unroll
        for (int mt = 0; mt < 4; ++mt) {
            f32x4 acc = {0.f, 0.f, 0.f, 0.f};
            #pragma unroll
            for (int kb = 0; kb < 4; ++kb)
                acc = __builtin_amdgcn_mfma_f32_16x16x32_bf16(af[mt][kb], bf[kb], acc, 0, 0, 0);
            #pragma unroll
            for (int r = 0; r < 4; ++r) {
                int row = mt*16 + l4*4 + r;        // row within tile
                float v = acc[r] + bv;
                v = v > 0.f ? v : 0.f;
                int byteoff = row*1024 + ((col*2) ^ ((row & 7) << 4));
                *(ushort*)(smem + byteoff) = f2bf(v);
            }
        }
    }
    __syncthreads();

    // ---- stage 2: wave handles n-tiles {2w, 2w+1} x 4 m-tiles, K=512 ----
    f32x4 acc2[4][2];
    #pragma unroll
    for (int mt = 0; mt < 4; ++mt)
        #pragma unroll
        for (int ntl = 0; ntl < 2; ++ntl) acc2[mt][ntl] = (f32x4){0.f,0.f,0.f,0.f};
    #pragma unroll 4
    for (int kb = 0; kb < 16; ++kb) {
        short8 a2[4];
        #pragma unroll
        for (int mt = 0; mt < 4; ++mt) {
            int row = mt*16 + l16;
            int kbyte = kb*64 + l4*16;
            a2[mt] = *(const short8*)(smem + row*1024 + (kbyte ^ ((row & 7) << 4)));
        }
        #pragma unroll
        for (int ntl = 0; ntl < 2; ++ntl) {
            int col = (wave*2 + ntl)*16 + l16;
            short8 bfr = *(const short8*)(w2 + (size_t)col*512 + kb*32 + l4*8);
            #pragma unroll
            for (int mt = 0; mt < 4; ++mt)
                acc2[mt][ntl] = __builtin_amdgcn_mfma_f32_16x16x32_bf16(a2[mt], bfr, acc2[mt][ntl], 0, 0, 0);
        }
    }
    __syncthreads();
    // ---- s = y + ff -> sbuf ----
    #pragma unroll
    for (int mt = 0; mt < 4; ++mt) {
        #pragma unroll
        for (int ntl = 0; ntl < 2; ++ntl) {
            int col = (wave*2 + ntl)*16 + l16;
            float bv = b2[col];
            #pragma unroll
            for (int r = 0; r < 4; ++r) {
                int row = mt*16 + l4*4 + r;
                int grow = base + row;
                int rc = grow < N ? grow : N - 1;
                sbuf[row*132 + col] = bf2f(yin[(size_t)rc*128 + col]) + acc2[mt][ntl][r] + bv;
            }
        }
    }
    __syncthreads();
    // ---- LN2: 4 threads per row ----
    {
        int row = threadIdx.x >> 2;     // 0..63
        int sub = threadIdx.x & 3;
        const float* sp = sbuf + row*132 + sub*32;
        float vals[32];
        float sum = 0.f, sq = 0.f;
        #pragma unroll
        for (int i = 0; i < 32; ++i) { float v = sp[i]; vals[i] = v; sum += v; sq += v*v; }
        sum += __shfl_xor(sum, 1); sq += __shfl_xor(sq, 1);
        sum += __shfl_xor(sum, 2); sq += __shfl_xor(sq, 2);
        float mean = sum * (1.f/128.f);
        float rstd = rsqrtf(sq*(1.f/128.f) - mean*mean + EPS);
        int grow = base + row;
        if (grow < N) {
            float* po = out + (size_t)grow*128 + sub*32;
            const float* pg = g2 + sub*32;
            const float* pb = be2 + sub*32;
            #pragma unroll
            for (int i = 0; i < 32; ++i)
                po[i] = (vals[i]-mean)*rstd*pg[i] + pb[i];
        }
    }
}

extern "C" void kernel_launch(void* const* d_in, const int* in_sizes, int n_in,
                              void* d_out, int out_size, void* d_ws, size_t ws_size,
                              hipStream_t stream) {
    (void)n_in; (void)out_size; (void)ws_size;
    const float* x   = (const float*)d_in[0];
    const int*   smp = (const int*)  d_in[1];
    const float* ipw = (const float*)d_in[2];
    const float* ipb = (const float*)d_in[3];
    const float* ow  = (const float*)d_in[4];
    const float* ob  = (const float*)d_in[5];
    const float* w1  = (const float*)d_in[6];
    const float* b1  = (const float*)d_in[7];
    const float* w2  = (const float*)d_in[8];
    const float* b2  = (const float*)d_in[9];
    const float* g1  = (const float*)d_in[10];
    const float* be1 = (const float*)d_in[11];
    const float* g2  = (const float*)d_in[12];
    const float* be2 = (const float*)d_in[13];
    const int N = in_sizes[0] / 128;

    ushort* qkv  = (ushort*)d_ws;                   // [N][384] bf16; Q region reused as ctx
    ushort* wqb  = qkv + (size_t)N * 384;           // 384*128
    ushort* wob  = wqb + 384*128;                   // 128*128
    ushort* w1b  = wob + 128*128;                   // 512*128
    ushort* w2b  = w1b + 512*128;                   // 128*512
    ushort* yb   = w2b + 128*512;                   // [N][128] bf16 staged y
    float*  outp = (float*)d_out;

    const int nb = (N + 63) / 64;
    k_prep <<<256,       256, 0, stream>>>(ipw, ow, w1, w2, wqb, wob, w1b, w2b);
    k_qkv  <<<nb,        256, 0, stream>>>(x, wqb, ipb, qkv, N);
    k_attn <<<(N+3)/4,   256, 0, stream>>>(qkv, smp, N);
    k_oproj<<<nb,        256, 0, stream>>>(qkv, wob, ob, x, g1, be1, yb, N);
    k_ffn  <<<nb,        256, 0, stream>>>(yb, w1b, b1, w2b, b2, g2, be2, outp, N);
}